// Round 9
// baseline (676.560 us; speedup 1.0000x reference)
//
#include <hip/hip_runtime.h>
#include <hip/hip_bf16.h>
#include <cstddef>
#include <cstdint>

#define NF 7

typedef short bf16x8 __attribute__((ext_vector_type(8)));
typedef float f32x16 __attribute__((ext_vector_type(16)));

__device__ __forceinline__ unsigned short f2bf(float f) {
    union { float f; unsigned u; } v; v.f = f;
    unsigned r = v.u + 0x7fffu + ((v.u >> 16) & 1u);   // round-to-nearest-even
    return (unsigned short)(r >> 16);
}

__device__ __forceinline__ float fast_silu(float a) {
    float e = __builtin_amdgcn_exp2f(a * -1.442695041f);
    return a * __builtin_amdgcn_rcpf(1.0f + e);
}

// feats layout: fxb[i][b][f0..7] bf16, f = {x, sin x, sin 2x, sin 4x, cos x, cos 2x, cos 4x, 1.0}
__global__ void feats_kernel(const float* __restrict__ in, unsigned short* __restrict__ out,
                             int din, int do_elu) {
    int t = blockIdx.x * blockDim.x + threadIdx.x;
    if (t >= din * 128) return;
    int b = t & 127;
    int i = t >> 7;
    float v = in[b * din + i];
    if (do_elu) v = (v > 0.0f) ? v : (__builtin_amdgcn_exp2f(v * 1.442695041f) - 1.0f);
    float s1, c1, s2, c2, s4, c4;
    sincosf(v, &s1, &c1);
    sincosf(2.0f * v, &s2, &c2);
    sincosf(4.0f * v, &s4, &c4);
    bf16x8 o;
    o[0] = (short)f2bf(v);
    o[1] = (short)f2bf(s1);
    o[2] = (short)f2bf(s2);
    o[3] = (short)f2bf(s4);
    o[4] = (short)f2bf(c1);
    o[5] = (short)f2bf(c2);
    o[6] = (short)f2bf(c4);
    o[7] = (short)0x3F80;           // 1.0 in bf16
    *(bf16x8*)(out + ((size_t)i * 128 + b) * 8) = o;
}

struct TaskW {
    bf16x8 A;
    float4 w2a, w2b, w2c, w2d;
};

// Same math as R6; software-pipelined step stream (task x bt), depth-2 B prefetch,
// next-task weight prefetch, epilogue of step k-1 covers MFMA latency of step k.
template <int DIN, int DOUT, int WCHUNK>
__global__ __launch_bounds__(256, 4) void kan_mfma(
    const unsigned short* __restrict__ fxb,  // [DIN][128][8] bf16
    const float* __restrict__ W1,            // [DIN][DOUT][32][7]
    const float* __restrict__ W2,            // [DIN][DOUT][32]
    const float* __restrict__ B1,            // [DIN][DOUT][32]
    const float* __restrict__ B2,            // [DIN][DOUT]
    float* __restrict__ out)                 // [128][DOUT], pre-zeroed, atomic accum
{
    const int j    = blockIdx.x;
    const int w    = threadIdx.x >> 6;
    const int lane = threadIdx.x & 63;
    const int hl   = lane & 31;
    const int hi   = lane >> 5;
    const int ib   = (blockIdx.y * 4 + w) * WCHUNK;

    const f32x16 CZ = {};

    // ---- helpers (macros keep everything statically indexed) ----
#define LOADW(tw, ii) do {                                                     \
    const size_t task_ = (size_t)(ii) * DOUT + j;                              \
    (tw).A = (bf16x8){0,0,0,0,0,0,0,0};                                        \
    if (hi == 0) {                                                             \
        const float* wr = W1 + task_ * 224 + (size_t)hl * 7;                   \
        float b1v = B1[task_ * 32 + hl];                                       \
        (tw).A[0] = (short)f2bf(wr[0]);                                        \
        (tw).A[1] = (short)f2bf(wr[1]);                                        \
        (tw).A[2] = (short)f2bf(wr[2]);                                        \
        (tw).A[3] = (short)f2bf(wr[3]);                                        \
        (tw).A[4] = (short)f2bf(wr[4]);                                        \
        (tw).A[5] = (short)f2bf(wr[5]);                                        \
        (tw).A[6] = (short)f2bf(wr[6]);                                        \
        (tw).A[7] = (short)f2bf(b1v);                                          \
    }                                                                          \
    const float* w2p = W2 + task_ * 32 + hi * 4;                               \
    (tw).w2a = *(const float4*)(w2p);                                          \
    (tw).w2b = *(const float4*)(w2p + 8);                                      \
    (tw).w2c = *(const float4*)(w2p + 16);                                     \
    (tw).w2d = *(const float4*)(w2p + 24);                                     \
    b2acc += B2[task_];                                                        \
} while (0)

#define LOADB(dst, ii, bt)                                                     \
    dst = *(const bf16x8*)(fxb + ((size_t)(ii) * 128 + (bt) * 32 + hl) * 8)

#define EPI(Csrc, tw, slot) do {                                               \
    float bacc = 0.f;                                                          \
    _Pragma("unroll")                                                          \
    for (int r = 0; r < 16; ++r) {                                             \
        float wv = (r < 4)  ? ((const float*)&(tw).w2a)[r & 3]                 \
                 : (r < 8)  ? ((const float*)&(tw).w2b)[r & 3]                 \
                 : (r < 12) ? ((const float*)&(tw).w2c)[r & 3]                 \
                            : ((const float*)&(tw).w2d)[r & 3];                \
        bacc = fmaf(fast_silu((Csrc)[r]), wv, bacc);                           \
    }                                                                          \
    accv[slot] += bacc;                                                        \
} while (0)

    float accv[4] = {0.f, 0.f, 0.f, 0.f};
    float b2acc = 0.f;
    const int N = WCHUNK * 4;

    TaskW cur, nxt;
    LOADW(cur, ib);
    nxt = cur;                       // silence uninitialized-use; overwritten before real use

    bf16x8 Bb, Bn;
    LOADB(Bb, ib, 0);                // B for step 0
    f32x16 Cp = __builtin_amdgcn_mfma_f32_32x32x16_bf16(cur.A, Bb, CZ, 0, 0, 0);
    LOADB(Bb, ib, 1);                // B for step 1

    #pragma unroll
    for (int k = 1; k < N; ++k) {
        const int t  = k >> 2;
        const int bt = k & 3;
        // depth-2 B prefetch: issue load for step k+1
        if (k + 1 < N) {
            const int t2 = (k + 1) >> 2;
            const int b2 = (k + 1) & 3;
            LOADB(Bn, ib + t2, b2);
        }
        // next-task weight prefetch, 3 epilogues before first use
        if (bt == 1 && t + 1 < WCHUNK) LOADW(nxt, ib + t + 1);
        // MFMA for step k (bt==0 starts the new task -> uses prefetched weights)
        f32x16 Cn = __builtin_amdgcn_mfma_f32_32x32x16_bf16(
            (bt == 0) ? nxt.A : cur.A, Bb, CZ, 0, 0, 0);
        // epilogue of step k-1 (uses OLD task weights at the boundary)
        EPI(Cp, cur, (k - 1) & 3);
        if (bt == 0) cur = nxt;
        Cp = Cn;
        Bb = Bn;
    }
    EPI(Cp, cur, (N - 1) & 3);

    // merge the two h-halves (rows differ by +4 across hi), then one atomic per (b, j)
    #pragma unroll
    for (int q = 0; q < 4; ++q) accv[q] += __shfl_xor(accv[q], 32);
    if (hi == 0) {
        #pragma unroll
        for (int q = 0; q < 4; ++q)
            atomicAdd(&out[(size_t)(q * 32 + hl) * DOUT + j], accv[q] + b2acc);
    }
#undef LOADW
#undef LOADB
#undef EPI
}

// GLU gate + residual + BatchNorm(batch axis), one block per output column j.
__device__ __forceinline__ int shidx(int k, int b) { return (k << 7) + ((b + k) & 127); }

__global__ __launch_bounds__(128) void glu_bn_kernel(
    const float* __restrict__ h2,     // [128][128]
    const float* __restrict__ resid,  // [128][128]
    const float* __restrict__ g1w, const float* __restrict__ g1b,
    const float* __restrict__ g2w, const float* __restrict__ g2b,
    const float* __restrict__ bnw, const float* __restrict__ bnb,
    float* __restrict__ out)          // [128][128]
{
    __shared__ float sh[128 * 128];
    const int j   = blockIdx.x;
    const int tid = threadIdx.x;

    for (int b2 = 0; b2 < 128; ++b2)
        sh[shidx(tid, b2)] = h2[(size_t)b2 * 128 + tid];
    __syncthreads();

    const float* g1r = g1w + (size_t)j * 128;
    const float* g2r = g2w + (size_t)j * 128;
    float d1 = g1b[j], d2 = g2b[j];
    for (int k = 0; k < 128; ++k) {
        float hv = sh[shidx(k, tid)];
        d1 = fmaf(hv, g1r[k], d1);
        d2 = fmaf(hv, g2r[k], d2);
    }
    float sg = __builtin_amdgcn_rcpf(1.0f + __builtin_amdgcn_exp2f(d1 * -1.442695041f));
    float v  = sg * d2 + resid[(size_t)tid * 128 + j];

    float s = v, ss = v * v;
    #pragma unroll
    for (int m = 1; m < 64; m <<= 1) {
        s  += __shfl_xor(s,  m, 64);
        ss += __shfl_xor(ss, m, 64);
    }
    __syncthreads();
    if ((tid & 63) == 0) { sh[(tid >> 6) * 2] = s; sh[(tid >> 6) * 2 + 1] = ss; }
    __syncthreads();
    s  = sh[0] + sh[2];
    ss = sh[1] + sh[3];
    float mean = s * (1.0f / 128.0f);
    float var  = ss * (1.0f / 128.0f) - mean * mean;
    out[(size_t)tid * 128 + j] = (v - mean) * rsqrtf(var + 1e-5f) * bnw[j] + bnb[j];
}

extern "C" void kernel_launch(void* const* d_in, const int* in_sizes, int n_in,
                              void* d_out, int out_size, void* d_ws, size_t ws_size,
                              hipStream_t stream) {
    const float* x      = (const float*)d_in[0];
    const float* fc1_W1 = (const float*)d_in[1];
    const float* fc1_W2 = (const float*)d_in[2];
    const float* fc1_B1 = (const float*)d_in[3];
    const float* fc1_B2 = (const float*)d_in[4];
    const float* fc2_W1 = (const float*)d_in[5];
    const float* fc2_W2 = (const float*)d_in[6];
    const float* fc2_B1 = (const float*)d_in[7];
    const float* fc2_B2 = (const float*)d_in[8];
    const float* sk_W1  = (const float*)d_in[9];
    const float* sk_W2  = (const float*)d_in[10];
    const float* sk_B1  = (const float*)d_in[11];
    const float* sk_B2  = (const float*)d_in[12];
    const float* g1w    = (const float*)d_in[13];
    const float* g1b    = (const float*)d_in[14];
    const float* g2w    = (const float*)d_in[15];
    const float* g2b    = (const float*)d_in[16];
    const float* bnw    = (const float*)d_in[17];
    const float* bnb    = (const float*)d_in[18];
    float* out = (float*)d_out;

    float* ws    = (float*)d_ws;
    float* h1    = ws;                       // 128*256 f32
    float* h2    = h1 + 128 * 256;           // 128*128 f32
    float* resid = h2 + 128 * 128;           // 128*128 f32
    unsigned short* fxb = (unsigned short*)(resid + 128 * 128);  // 128*128*8 bf16
    unsigned short* fhb = fxb + 128 * 128 * 8;                   // 256*128*8 bf16

    hipMemsetAsync(h1, 0, (size_t)(128 * 256 + 2 * 128 * 128) * sizeof(float), stream);

    feats_kernel<<<dim3(64), 256, 0, stream>>>(x, fxb, 128, 0);

    kan_mfma<128, 256, 8><<<dim3(256, 4), 256, 0, stream>>>(
        fxb, fc1_W1, fc1_W2, fc1_B1, fc1_B2, h1);
    kan_mfma<128, 128, 8><<<dim3(128, 4), 256, 0, stream>>>(
        fxb, sk_W1, sk_W2, sk_B1, sk_B2, resid);

    feats_kernel<<<dim3(128), 256, 0, stream>>>(h1, fhb, 256, 1);

    kan_mfma<256, 128, 8><<<dim3(128, 8), 256, 0, stream>>>(
        fhb, fc2_W1, fc2_W2, fc2_B1, fc2_B2, h2);

    glu_bn_kernel<<<dim3(128), 128, 0, stream>>>(
        h2, resid, g1w, g1b, g2w, g2b, bnw, bnb, out);
}